// Round 2
// baseline (3302.389 us; speedup 1.0000x reference)
//
#include <hip/hip_runtime.h>
#include <math.h>

// ---- problem dims ----
#define B_    8
#define T_    256
#define S_    16
#define H_    1024
#define NH_   16
#define L_    6
#define NI_   4096
#define TIME_ 8
#define T3_   768           // 3*T
#define DH_   64            // H/NH
#define BT_   2048          // B*T
#define ROWS_ 6144          // B*T3
#define KE_   1032          // H + TIME
#define KEP_  1056          // KE padded to multiple of 32
#define NEGV  (-10000.0f)

typedef unsigned short u16;
typedef short bf16x8 __attribute__((ext_vector_type(8)));   // 8 bf16 in 4 VGPRs
typedef float f32x4 __attribute__((ext_vector_type(4)));

__device__ __forceinline__ float bf2f(u16 u) {
    union { unsigned int i; float f; } x; x.i = ((unsigned int)u) << 16; return x.f;
}
__device__ __forceinline__ u16 f2bf(float f) {
    union { float f; unsigned int i; } x; x.f = f;
    unsigned int r = x.i + 0x7FFFu + ((x.i >> 16) & 1u);   // RNE
    return (u16)(r >> 16);
}
// tanh-form GELU via hw exp: |err vs exact erf-gelu| < ~6e-4 (threshold 6.8e-2)
__device__ __forceinline__ float gelu_fast(float x) {
    float y = 0.7978845608028654f * (x + 0.044715f * x * x * x);
    float e = __expf(2.0f * y);
    float t = 1.0f - 2.0f / (e + 1.0f);
    return 0.5f * x * (1.0f + t);
}

// async global->LDS 16B: lds dest is wave-uniform base + lane*16 (m97 pattern)
__device__ __forceinline__ void gll16(const u16* g, u16* l) {
    __builtin_amdgcn_global_load_lds(
        (const __attribute__((address_space(1))) unsigned int*)g,
        (__attribute__((address_space(3))) unsigned int*)l,
        16, 0, 0);
}

// =====================================================================
// bf16 MFMA GEMM core, double-buffered, XCD-swizzled 1D grid.
// C(M,N) = A(M,K) @ Bt(N,K)^T + bias. BMx128x32 tiles.
// Swizzle: bids sharing an A row-panel are {base, base+8, ..} -> same XCD
// under round-robin dispatch, temporally adjacent -> A-panel L2 reuse.
// Requires (M/BM) % 8 == 0.
// EPI: 0 = bias -> f32, 1 = bias + residual(f32) -> f32,
//      2 = bias -> bf16, 3 = bias + gelu -> bf16,
//      4 = split-K partial: atomicAdd into f32 (bias only when addb)
// koff/klen: K-range this block accumulates (split-K). Row stride stays K.
// =====================================================================
template <int EPI, int BM>
__device__ __forceinline__ void mgemm_core(
    const u16* __restrict__ A, const u16* __restrict__ Bt,
    const float* __restrict__ bias, float* __restrict__ outf,
    u16* __restrict__ outb, const float* __restrict__ res,
    int N, int K, int koff, int klen, bool addb)
{
    constexpr int MT = (BM == 128) ? 4 : 2;     // 16-row m-tiles per wave
    __shared__ u16 Als[2][BM * 32];
    __shared__ u16 Bls[2][128 * 32];
    const int tid = threadIdx.x;

    // ---- swizzled block mapping ----
    const int nbx = N >> 7;
    const int bid = blockIdx.x;
    const int G = nbx << 3;
    const int grp = bid / G;
    const int g = bid - grp * G;
    const int bm = (grp * 8 + (g & 7)) * BM;
    const int bn = (g >> 3) * 128;

    const int lane = tid & 63;
    const int w = tid >> 6;                      // wave 0..3
    const int wr = (BM == 128) ? (w >> 1) : (w & 1);
    const int wc = (BM == 128) ? (w & 1) : (w >> 1);
    const int lrow = lane & 15;
    const int lk = lane >> 4;

    f32x4 acc[MT][4] = {};

    auto stage = [&](int buf, int kk) {
        if (BM == 128) {
            #pragma unroll
            for (int s = 0; s < 2; ++s) {
                const int gb = w * 64 + s * 256;          // wave-uniform granule base
                const int j = gb >> 7, m0 = gb & 127;
                gll16(A + (size_t)(bm + m0 + lane) * K + kk + j * 8, Als[buf] + gb * 8);
            }
        } else {
            gll16(A + (size_t)(bm + lane) * K + kk + w * 8, Als[buf] + w * 64 * 8);
        }
        #pragma unroll
        for (int s = 0; s < 2; ++s) {
            const int gb = w * 64 + s * 256;
            const int j = gb >> 7, m0 = gb & 127;
            gll16(Bt + (size_t)(bn + m0 + lane) * K + kk + j * 8, Bls[buf] + gb * 8);
        }
    };

    const int niter = klen >> 5;
    stage(0, koff);
    for (int i = 0; i < niter; ++i) {
        __syncthreads();                          // loads into buf[i&1] landed
        if (i + 1 < niter) stage((i + 1) & 1, koff + (i + 1) * 32);
        const bf16x8* Af = (const bf16x8*)Als[i & 1];
        const bf16x8* Bf = (const bf16x8*)Bls[i & 1];
        bf16x8 af[MT], bfr[4];
        #pragma unroll
        for (int tm = 0; tm < MT; ++tm)
            af[tm] = Af[lk * BM + wr * (MT * 16) + tm * 16 + lrow];
        #pragma unroll
        for (int tn = 0; tn < 4; ++tn)
            bfr[tn] = Bf[lk * 128 + wc * 64 + tn * 16 + lrow];
        #pragma unroll
        for (int tm = 0; tm < MT; ++tm)
            #pragma unroll
            for (int tn = 0; tn < 4; ++tn)
                acc[tm][tn] = __builtin_amdgcn_mfma_f32_16x16x32_bf16(
                    af[tm], bfr[tn], acc[tm][tn], 0, 0, 0);
    }

    // ---- epilogue: D row = quad*4+reg, col = lane&15 (per 16x16 tile) ----
    int cg[4]; float bv[4];
    #pragma unroll
    for (int tn = 0; tn < 4; ++tn) {
        cg[tn] = bn + wc * 64 + tn * 16 + lrow;
        bv[tn] = addb ? bias[cg[tn]] : 0.0f;
    }
    #pragma unroll
    for (int tm = 0; tm < MT; ++tm) {
        const int rbase = bm + wr * (MT * 16) + tm * 16 + lk * 4;
        #pragma unroll
        for (int r = 0; r < 4; ++r) {
            const size_t rowoff = (size_t)(rbase + r) * N;
            #pragma unroll
            for (int tn = 0; tn < 4; ++tn) {
                float v = acc[tm][tn][r] + bv[tn];
                const size_t idx = rowoff + cg[tn];
                if (EPI == 0) outf[idx] = v;
                else if (EPI == 1) outf[idx] = v + res[idx];
                else if (EPI == 2) outb[idx] = f2bf(v);
                else if (EPI == 3) { outb[idx] = f2bf(gelu_fast(v)); }
                else { unsafeAtomicAdd(outf + idx, v); }   // EPI == 4, split-K
            }
        }
    }
}

template <int EPI, int BM>
__global__ __launch_bounds__(256) void mgemm(
    const u16* __restrict__ A, const u16* __restrict__ Bt,
    const float* __restrict__ bias, float* __restrict__ outf,
    u16* __restrict__ outb, const float* __restrict__ res,
    int N, int K)
{
    mgemm_core<EPI, BM>(A, Bt, bias, outf, outb, res, N, K, 0, K, true);
}

// split-K variant: grid.y = split index; partials atomically accumulated
// into outf (which must already hold the residual). Bias added by split 0.
template <int EPI, int BM>
__global__ __launch_bounds__(256) void mgemm_sk(
    const u16* __restrict__ A, const u16* __restrict__ Bt,
    const float* __restrict__ bias, float* __restrict__ outf,
    u16* __restrict__ outb, const float* __restrict__ res,
    int N, int K, int nsplit)
{
    const int split = blockIdx.y;
    const int klen = K / nsplit;
    mgemm_core<EPI, BM>(A, Bt, bias, outf, outb, res, N, K,
                        split * klen, klen, split == 0);
}

// fused embed GEMMs: z = 0(s) / 1(a) / 2(r)
__global__ __launch_bounds__(256) void mgemm_embed(
    const u16* __restrict__ U, const u16* __restrict__ Wt,
    const float* __restrict__ b0, const float* __restrict__ b1,
    const float* __restrict__ b2, float* __restrict__ out)
{
    const int z = blockIdx.z;
    const float* bias = (z == 0) ? b0 : (z == 1) ? b1 : b2;
    mgemm_core<0, 64>(U + (size_t)z * BT_ * KEP_, Wt + (size_t)z * H_ * KEP_,
                      bias, out + (size_t)z * BT_ * H_, nullptr, nullptr,
                      H_, KEP_, 0, KEP_, true);
}

// =====================================================================
// Vectorized weight transpose + fp32->bf16: W[K][N] -> Wt[N][Kpad].
// 32(K) x 64(N) tile, float4 loads, ushort4 stores. Zero-fill k >= K.
// =====================================================================
__device__ __forceinline__ void convT_core(
    const float* __restrict__ W, u16* __restrict__ Wt, int K, int N, int Kpad)
{
    __shared__ float tile[32][65];
    const int k0 = blockIdx.y * 32, n0 = blockIdx.x * 64;
    const int tid = threadIdx.x;
    #pragma unroll
    for (int p = 0; p < 2; ++p) {
        const int kr = (tid >> 4) + p * 16;
        const int nc = (tid & 15) * 4;
        const int k = k0 + kr;
        float4 v = make_float4(0.f, 0.f, 0.f, 0.f);
        if (k < K) v = *(const float4*)(W + (size_t)k * N + n0 + nc);
        tile[kr][nc + 0] = v.x; tile[kr][nc + 1] = v.y;
        tile[kr][nc + 2] = v.z; tile[kr][nc + 3] = v.w;
    }
    __syncthreads();
    #pragma unroll
    for (int p = 0; p < 2; ++p) {
        const int idx = tid + p * 256;
        const int n = idx >> 3, kq = (idx & 7) * 4;
        ushort4 o;
        o.x = f2bf(tile[kq + 0][n]); o.y = f2bf(tile[kq + 1][n]);
        o.z = f2bf(tile[kq + 2][n]); o.w = f2bf(tile[kq + 3][n]);
        *(ushort4*)(Wt + (size_t)(n0 + n) * Kpad + k0 + kq) = o;
    }
}

__global__ __launch_bounds__(256) void convTv(
    const float* __restrict__ W, u16* __restrict__ Wt, int K, int N, int Kpad)
{
    convT_core(W, Wt, K, N, Kpad);
}

// embed weights: z = 0(ts)/1(ta)/2(tr), each [KE_][H_] -> [H_][KEP_]
__global__ __launch_bounds__(256) void convT_embed(
    const float* __restrict__ W0, const float* __restrict__ W1,
    const float* __restrict__ W2, u16* __restrict__ Wt)
{
    const int z = blockIdx.z;
    const float* W = (z == 0) ? W0 : (z == 1) ? W1 : W2;
    convT_core(W, Wt + (size_t)z * H_ * KEP_, KE_, H_, KEP_);
}

// per-layer QKV+O transpose (z=0..3) + qkv bias pack
__global__ __launch_bounds__(256) void convT4v(
    const float* __restrict__ Wq, const float* __restrict__ Wk,
    const float* __restrict__ Wv, const float* __restrict__ Wo,
    const float* __restrict__ bq, const float* __restrict__ bk,
    const float* __restrict__ bv,
    u16* __restrict__ WQKVt, u16* __restrict__ Wot, float* __restrict__ bqkv)
{
    const int z = blockIdx.z;
    const float* W = (z == 0) ? Wq : (z == 1) ? Wk : (z == 2) ? Wv : Wo;
    u16* Wt = (z == 3) ? Wot : WQKVt + (size_t)z * H_ * H_;
    convT_core(W, Wt, H_, H_, H_);
    if (blockIdx.x == 0 && blockIdx.y == 0 && z < 3) {
        const float* bsrc = (z == 0) ? bq : (z == 1) ? bk : bv;
        #pragma unroll
        for (int u = 0; u < 4; ++u) {
            int i = threadIdx.x + u * 256;
            bqkv[z * H_ + i] = bsrc[i];
        }
    }
}

// =====================================================================
// embedding pre-stage
// =====================================================================
__global__ __launch_bounds__(256) void embed_pre_kernel(
    const float* __restrict__ states, const float* __restrict__ actions,
    const float* __restrict__ rtgs, const float* __restrict__ mean,
    const float* __restrict__ stdv, const float* __restrict__ W_es,
    const float* __restrict__ b_es, const float* __restrict__ W_ea,
    const float* __restrict__ b_ea, const float* __restrict__ W_er,
    const float* __restrict__ b_er, const float* __restrict__ E_t,
    const int* __restrict__ timesteps,
    u16* __restrict__ Us, u16* __restrict__ Ua, u16* __restrict__ Ur)
{
    const int bt  = blockIdx.x;
    const int tid = threadIdx.x;
    __shared__ float sn[S_];
    __shared__ float tev[TIME_];
    if (tid < S_) sn[tid] = (states[bt * S_ + tid] - mean[tid]) / (stdv[tid] + 1e-9f);
    if (tid < TIME_) {
        int ts = timesteps[bt];
        tev[tid] = E_t[ts * TIME_ + tid];
    }
    __syncthreads();
    const float av = actions[bt];
    const float rv = rtgs[bt];
    const size_t rowo = (size_t)bt * KEP_;
    #pragma unroll
    for (int u = 0; u < 4; ++u) {
        int n = tid + u * 256;
        float accs = b_es[n];
        #pragma unroll
        for (int i = 0; i < S_; ++i) accs += sn[i] * W_es[i * H_ + n];
        Us[rowo + n] = f2bf(accs);
        Ua[rowo + n] = f2bf(av * W_ea[n] + b_ea[n]);
        Ur[rowo + n] = f2bf(rv * W_er[n] + b_er[n]);
    }
    if (tid < TIME_) {
        u16 tv = f2bf(tev[tid]);
        Us[rowo + H_ + tid] = tv;
        Ua[rowo + H_ + tid] = tv;
        Ur[rowo + H_ + tid] = tv;
    }
    if (tid < KEP_ - KE_) {
        Us[rowo + KE_ + tid] = 0;
        Ua[rowo + KE_ + tid] = 0;
        Ur[rowo + KE_ + tid] = 0;
    }
}

// =====================================================================
// LayerNorm over rows of 1024
// =====================================================================
template <bool BF16OUT>
__device__ __forceinline__ void ln_body(const float* __restrict__ src,
                                        const float* __restrict__ g,
                                        const float* __restrict__ b,
                                        void* __restrict__ dst,
                                        float* red, int tid)
{
    float v[4];
    #pragma unroll
    for (int u = 0; u < 4; ++u) v[u] = src[tid + u * 256];
    float s = v[0] + v[1] + v[2] + v[3];
    red[tid] = s; __syncthreads();
    for (int off = 128; off > 0; off >>= 1) {
        if (tid < off) red[tid] += red[tid + off];
        __syncthreads();
    }
    const float mean = red[0] * (1.0f / H_);
    __syncthreads();
    float ss = 0.0f;
    #pragma unroll
    for (int u = 0; u < 4; ++u) { float d = v[u] - mean; ss += d * d; }
    red[tid] = ss; __syncthreads();
    for (int off = 128; off > 0; off >>= 1) {
        if (tid < off) red[tid] += red[tid + off];
        __syncthreads();
    }
    const float var = red[0] * (1.0f / H_);
    const float rs = rsqrtf(var + 1e-5f);
    #pragma unroll
    for (int u = 0; u < 4; ++u) {
        int col = tid + u * 256;
        float y = (v[u] - mean) * rs * g[col] + b[col];
        if (BF16OUT) ((u16*)dst)[col] = f2bf(y);
        else ((float*)dst)[col] = y;
    }
}

__global__ __launch_bounds__(256) void ln_bf16_kernel(
    const float* __restrict__ X, const float* __restrict__ g,
    const float* __restrict__ b, u16* __restrict__ Y)
{
    __shared__ float red[256];
    const size_t row = blockIdx.x;
    ln_body<true>(X + row * H_, g, b, Y + row * H_, red, threadIdx.x);
}

__global__ __launch_bounds__(256) void interleave_eln_kernel(
    const float* __restrict__ RE, const float* __restrict__ SE,
    const float* __restrict__ AE, const float* __restrict__ g,
    const float* __restrict__ b, float* __restrict__ X)
{
    __shared__ float red[256];
    const int row = blockIdx.x;
    const int bi = row / T3_;
    const int rem = row % T3_;
    const int t = rem / 3, slot = rem % 3;
    const float* src = (slot == 0 ? RE : (slot == 1 ? SE : AE)) + (size_t)(bi * T_ + t) * H_;
    ln_body<false>(src, g, b, X + (size_t)row * H_, red, threadIdx.x);
}

// =====================================================================
// MFMA flash attention. Block = 64 Q-rows x (head, batch); wave = 16 rows.
// =====================================================================
__global__ __launch_bounds__(256) void attn_kernel(
    const u16* __restrict__ QKV, const float* __restrict__ amask,
    u16* __restrict__ Y)
{
    const int qt = blockIdx.x;   // 0..11
    const int h  = blockIdx.y;   // 0..15
    const int b  = blockIdx.z;   // 0..7
    const int tid = threadIdx.x;
    const int lane = tid & 63, w = tid >> 6;
    const int l15 = lane & 15, quad = lane >> 4;

    __shared__ u16 Kls[64][72];      // row-major K tile (+8 pad)
    __shared__ u16 Vt[64][72];       // transposed V tile: Vt[dh][token]
    __shared__ u16 Pls[4][16][72];   // per-wave P tile
    __shared__ float padv[64];

    const u16* Qbase = QKV + (size_t)b * T3_ * 3072 + h * 64;
    const u16* Kbase = Qbase + 1024;
    const u16* Vbase = Qbase + 2048;

    bf16x8 qf[2];
    {
        const u16* qp = Qbase + (size_t)(qt * 64 + w * 16 + l15) * 3072 + quad * 8;
        qf[0] = *(const bf16x8*)qp;
        qf[1] = *(const bf16x8*)(qp + 32);
    }

    float m_i[4], l_i[4];
    f32x4 o[4] = {};
    #pragma unroll
    for (int r = 0; r < 4; ++r) { m_i[r] = -3.0e30f; l_i[r] = 0.0f; }

    const int qr0 = qt * 64 + w * 16 + quad * 4;

    for (int kt = 0; kt <= qt; ++kt) {
        #pragma unroll
        for (int s = 0; s < 2; ++s) {
            const int c = tid + s * 256;
            const int tok = c >> 3, cb = c & 7;
            const size_t go = (size_t)(kt * 64 + tok) * 3072 + cb * 8;
            *(uint4*)&Kls[tok][cb * 8] = *(const uint4*)(Kbase + go);
            uint4 vv = *(const uint4*)(Vbase + go);
            const u16* vs = (const u16*)&vv;
            #pragma unroll
            for (int j = 0; j < 8; ++j) Vt[cb * 8 + j][tok] = vs[j];
        }
        if (tid < 64)
            padv[tid] = (1.0f - amask[b * T_ + (kt * 64 + tid) / 3]) * NEGV;
        __syncthreads();

        f32x4 sacc[4];
        #pragma unroll
        for (int nt = 0; nt < 4; ++nt) {
            bf16x8 kf0 = *(const bf16x8*)&Kls[nt * 16 + l15][quad * 8];
            bf16x8 kf1 = *(const bf16x8*)&Kls[nt * 16 + l15][32 + quad * 8];
            f32x4 z = {};
            z = __builtin_amdgcn_mfma_f32_16x16x32_bf16(qf[0], kf0, z, 0, 0, 0);
            sacc[nt] = __builtin_amdgcn_mfma_f32_16x16x32_bf16(qf[1], kf1, z, 0, 0, 0);
        }

        float sv[4][4];
        float rmax[4] = {-3.0e30f, -3.0e30f, -3.0e30f, -3.0e30f};
        #pragma unroll
        for (int nt = 0; nt < 4; ++nt) {
            const int jc = kt * 64 + nt * 16 + l15;
            const float pv = padv[nt * 16 + l15];
            #pragma unroll
            for (int r = 0; r < 4; ++r) {
                float v = (jc <= qr0 + r) ? sacc[nt][r] * 0.125f : NEGV;
                v += pv;
                sv[nt][r] = v;
                rmax[r] = fmaxf(rmax[r], v);
            }
        }
        #pragma unroll
        for (int m = 1; m < 16; m <<= 1)
            #pragma unroll
            for (int r = 0; r < 4; ++r)
                rmax[r] = fmaxf(rmax[r], __shfl_xor(rmax[r], m, 64));
        float al[4], rsum[4];
        #pragma unroll
        for (int r = 0; r < 4; ++r) {
            const float mn = fmaxf(m_i[r], rmax[r]);
            al[r] = __expf(m_i[r] - mn);
            m_i[r] = mn;
            float sum = 0.0f;
            #pragma unroll
            for (int nt = 0; nt < 4; ++nt) {
                float p = __expf(sv[nt][r] - mn);
                sv[nt][r] = p; sum += p;
            }
            rsum[r] = sum;
        }
        #pragma unroll
        for (int m = 1; m < 16; m <<= 1)
            #pragma unroll
            for (int r = 0; r < 4; ++r)
                rsum[r] += __shfl_xor(rsum[r], m, 64);
        #pragma unroll
        for (int r = 0; r < 4; ++r)
            l_i[r] = l_i[r] * al[r] + rsum[r];

        #pragma unroll
        for (int nt = 0; nt < 4; ++nt)
            #pragma unroll
            for (int r = 0; r < 4; ++r)
                Pls[w][quad * 4 + r][nt * 16 + l15] = f2bf(sv[nt][r]);
        #pragma unroll
        for (int dt = 0; dt < 4; ++dt)
            #pragma unroll
            for (int r = 0; r < 4; ++r)
                o[dt][r] *= al[r];

        bf16x8 pf0 = *(const bf16x8*)&Pls[w][l15][quad * 8];
        bf16x8 pf1 = *(const bf16x8*)&Pls[w][l15][32 + quad * 8];
        #pragma unroll
        for (int dt = 0; dt < 4; ++dt) {
            bf16x8 vf0 = *(const bf16x8*)&Vt[dt * 16 + l15][quad * 8];
            bf16x8 vf1 = *(const bf16x8*)&Vt[dt * 16 + l15][32 + quad * 8];
            o[dt] = __builtin_amdgcn_mfma_f32_16x16x32_bf16(pf0, vf0, o[dt], 0, 0, 0);
            o[dt] = __builtin_amdgcn_mfma_f32_16x16x32_bf16(pf1, vf1, o[dt], 0, 0, 0);
        }
        __syncthreads();
    }

    #pragma unroll
    for (int r = 0; r < 4; ++r) {
        const float inv = 1.0f / l_i[r];
        const size_t row = (size_t)b * T3_ + qt * 64 + w * 16 + quad * 4 + r;
        #pragma unroll
        for (int dt = 0; dt < 4; ++dt)
            Y[row * H_ + h * 64 + dt * 16 + l15] = f2bf(o[dt][r] * inv);
    }
}

// =====================================================================
// action head
// =====================================================================
__global__ __launch_bounds__(256) void head_kernel(
    const float* __restrict__ X, const float* __restrict__ W_pa,
    const float* __restrict__ b_pa, float* __restrict__ out)
{
    __shared__ float red[256];
    const int row = blockIdx.x;
    const int b = row / T_, t = row % T_;
    const float* x = X + ((size_t)b * T3_ + 3 * t + 1) * H_;
    const int tid = threadIdx.x;
    float s = 0.0f;
    #pragma unroll
    for (int u = 0; u < 4; ++u) {
        int col = tid + u * 256;
        s += x[col] * W_pa[col];
    }
    red[tid] = s; __syncthreads();
    for (int off = 128; off > 0; off >>= 1) {
        if (tid < off) red[tid] += red[tid + off];
        __syncthreads();
    }
    if (tid == 0) out[row] = red[0] + b_pa[0];
}

// =====================================================================
extern "C" void kernel_launch(void* const* d_in, const int* in_sizes, int n_in,
                              void* d_out, int out_size, void* d_ws, size_t ws_size,
                              hipStream_t stream)
{
    const float* states  = (const float*)d_in[0];
    const float* actions = (const float*)d_in[1];
    const float* rtgs    = (const float*)d_in[2];
    const float* amask   = (const float*)d_in[3];
    const float* smean   = (const float*)d_in[4];
    const float* sstd    = (const float*)d_in[5];
    const float* W_es    = (const float*)d_in[6];
    const float* b_es    = (const float*)d_in[7];
    const float* W_ea    = (const float*)d_in[8];
    const float* b_ea    = (const float*)d_in[9];
    const float* W_er    = (const float*)d_in[10];
    const float* b_er    = (const float*)d_in[11];
    const float* E_t     = (const float*)d_in[12];
    const float* W_ts    = (const float*)d_in[13];
    const float* b_ts    = (const float*)d_in[14];
    const float* W_ta    = (const float*)d_in[15];
    const float* b_ta    = (const float*)d_in[16];
    const float* W_tr    = (const float*)d_in[17];
    const float* b_tr    = (const float*)d_in[18];
    const float* eln_g   = (const float*)d_in[19];
    const float* eln_b   = (const float*)d_in[20];
    const float* ln1_g   = (const float*)d_in[21];
    const float* ln1_b   = (const float*)d_in[22];
    const float* ln2_g   = (const float*)d_in[23];
    const float* ln2_b   = (const float*)d_in[24];
    const float* Wq      = (const float*)d_in[25];
    const float* bq      = (const float*)d_in[26];
    const float* Wk      = (const float*)d_in[27];
    const float* bk      = (const float*)d_in[28];
    const float* Wv      = (const float*)d_in[29];
    const float* bv      = (const float*)d_in[30];
    const float* Wo      = (const float*)d_in[31];
    const float* bo      = (const float*)d_in[32];
    const float* W1      = (const float*)d_in[33];
    const float* b1      = (const float*)d_in[34];
    const float* W2      = (const float*)d_in[35];
    const float* b2      = (const float*)d_in[36];
    const float* W_pa    = (const float*)d_in[37];
    const float* b_pa    = (const float*)d_in[38];
    const int*   tsteps  = (const int*)d_in[39];
    float* out = (float*)d_out;

    // ---- workspace layout (bytes) ----
    char* base = (char*)d_ws;
    float* X    = (float*)base;                        // 25,165,824
    u16*   Hb   = (u16*)(base + 25165824);             // 12,582,912
    u16*   QKVb = (u16*)(base + 37748736);             // 37,748,736
    u16*   MIDb = (u16*)(base + 75497472);             // 50,331,648
    u16*   Wbuf = (u16*)(base + 125829120);            // 25,165,824 (end 150,994,944)

    float* bqkv = (float*)MIDb;
    u16* U_s = MIDb;
    u16* U_a = MIDb + (size_t)BT_ * KEP_;
    u16* U_r = MIDb + (size_t)2 * BT_ * KEP_;
    float* SE = (float*)QKVb;                          // SE, AE, RE consecutive
    float* AE = SE + (size_t)BT_ * H_;
    float* RE = AE + (size_t)BT_ * H_;
    u16* Wemb = Wbuf;                                  // 3 x [H_][KEP_]

    u16* WQKVt = Wbuf;                                 // [3072][1024]
    u16* Wot   = Wbuf + (size_t)3072 * 1024;           // [1024][1024]
    u16* W1t   = Wbuf + (size_t)4096 * 1024;           // [4096][1024]
    u16* W2t   = Wbuf + (size_t)8192 * 1024;           // [1024][4096]

    // ---- embedding ----
    embed_pre_kernel<<<BT_, 256, 0, stream>>>(
        states, actions, rtgs, smean, sstd, W_es, b_es, W_ea, b_ea,
        W_er, b_er, E_t, tsteps, U_s, U_a, U_r);

    dim3 gCvE(H_ / 64, KEP_ / 32, 3);                  // 16 x 33 x 3
    convT_embed<<<gCvE, 256, 0, stream>>>(W_ts, W_ta, W_tr, Wemb);

    dim3 gEmb((H_ / 128) * (BT_ / 64), 1, 3);          // 256 x 1 x 3
    mgemm_embed<<<gEmb, 256, 0, stream>>>(U_s, Wemb, b_ts, b_ta, b_tr, SE);

    interleave_eln_kernel<<<ROWS_, 256, 0, stream>>>(RE, SE, AE, eln_g, eln_b, X);

    // ---- transformer layers ----
    dim3 gCv4(H_ / 64, H_ / 32, 4);                    // QKV+O transpose
    dim3 gCvM1(NI_ / 64, H_ / 32);                     // W1
    dim3 gCvM2(H_ / 64, NI_ / 32);                     // W2
    const int gQKV = (3072 / 128) * (ROWS_ / 128);     // 1152
    const int gM1  = (NI_ / 128) * (ROWS_ / 128);      // 1536
    dim3 gOsk((H_ / 128) * (ROWS_ / 128), 2);          // 384 x 2 splits = 768
    dim3 gAttn(T3_ / 64, NH_, B_);                     // 12 x 16 x 8

    for (int l = 0; l < L_; ++l) {
        const size_t wOff = (size_t)l * H_ * H_;
        const size_t bOff = (size_t)l * H_;
        const size_t w1Off = (size_t)l * H_ * NI_;
        const size_t b1Off = (size_t)l * NI_;

        convT4v<<<gCv4, 256, 0, stream>>>(
            Wq + wOff, Wk + wOff, Wv + wOff, Wo + wOff,
            bq + bOff, bk + bOff, bv + bOff, WQKVt, Wot, bqkv);
        convTv<<<gCvM1, 256, 0, stream>>>(W1 + w1Off, W1t, H_, NI_, H_);
        convTv<<<gCvM2, 256, 0, stream>>>(W2 + w1Off, W2t, NI_, H_, NI_);

        ln_bf16_kernel<<<ROWS_, 256, 0, stream>>>(X, ln1_g + bOff, ln1_b + bOff, Hb);
        mgemm<2, 128><<<gQKV, 256, 0, stream>>>(Hb, WQKVt, bqkv, nullptr, QKVb, nullptr, 3072, H_);
        attn_kernel<<<gAttn, 256, 0, stream>>>(QKVb, amask, Hb);
        // O-proj: split-K=2, atomic accumulate into X (X holds residual)
        mgemm_sk<4, 128><<<gOsk, 256, 0, stream>>>(Hb, Wot, bo + bOff, X, nullptr, nullptr, H_, H_, 2);
        ln_bf16_kernel<<<ROWS_, 256, 0, stream>>>(X, ln2_g + bOff, ln2_b + bOff, Hb);
        mgemm<3, 128><<<gM1, 256, 0, stream>>>(Hb, W1t, b1 + b1Off, nullptr, MIDb, nullptr, NI_, H_);
        // FFN2: split-K=2, atomic accumulate into X (X holds residual)
        mgemm_sk<4, 128><<<gOsk, 256, 0, stream>>>(MIDb, W2t, b2 + bOff, X, nullptr, nullptr, H_, NI_, 2);
    }

    head_kernel<<<BT_, 256, 0, stream>>>(X, W_pa, b_pa, out);
}

// Round 3
// 3274.020 us; speedup vs baseline: 1.0087x; 1.0087x over previous
//
#include <hip/hip_runtime.h>
#include <math.h>

// ---- problem dims ----
#define B_    8
#define T_    256
#define S_    16
#define H_    1024
#define NH_   16
#define L_    6
#define NI_   4096
#define TIME_ 8
#define T3_   768           // 3*T
#define DH_   64            // H/NH
#define BT_   2048          // B*T
#define ROWS_ 6144          // B*T3
#define KE_   1032          // H + TIME
#define KEP_  1056          // KE padded to multiple of 32
#define NEGV  (-10000.0f)

typedef unsigned short u16;
typedef short bf16x8 __attribute__((ext_vector_type(8)));   // 8 bf16 in 4 VGPRs
typedef float f32x4 __attribute__((ext_vector_type(4)));

__device__ __forceinline__ float bf2f(u16 u) {
    union { unsigned int i; float f; } x; x.i = ((unsigned int)u) << 16; return x.f;
}
__device__ __forceinline__ u16 f2bf(float f) {
    union { float f; unsigned int i; } x; x.f = f;
    unsigned int r = x.i + 0x7FFFu + ((x.i >> 16) & 1u);   // RNE
    return (u16)(r >> 16);
}
// tanh-form GELU via hw exp: |err vs exact erf-gelu| < ~6e-4 (threshold 6.8e-2)
__device__ __forceinline__ float gelu_fast(float x) {
    float y = 0.7978845608028654f * (x + 0.044715f * x * x * x);
    float e = __expf(2.0f * y);
    float t = 1.0f - 2.0f / (e + 1.0f);
    return 0.5f * x * (1.0f + t);
}

// async global->LDS 16B: lds dest is wave-uniform base + lane*16 (m97 pattern)
__device__ __forceinline__ void gll16(const u16* g, u16* l) {
    __builtin_amdgcn_global_load_lds(
        (const __attribute__((address_space(1))) unsigned int*)g,
        (__attribute__((address_space(3))) unsigned int*)l,
        16, 0, 0);
}

// =====================================================================
// bf16 MFMA GEMM core, double-buffered, XCD-swizzled 1D grid.
// C(M,N) = A(M,K) @ Bt(N,K)^T + bias. BMx128x32 tiles.
// Requires (M/BM) % 8 == 0.
// EPI: 0 = bias -> f32, 1 = bias + residual(f32) -> f32,
//      2 = bias -> bf16, 3 = bias + gelu -> bf16,
//      4 = split-K partial: atomicAdd into f32 (bias only when addb)
// koff/klen: K-range this block accumulates (split-K). Row stride stays K.
// =====================================================================
template <int EPI, int BM>
__device__ __forceinline__ void mgemm_core(
    const u16* __restrict__ A, const u16* __restrict__ Bt,
    const float* __restrict__ bias, float* __restrict__ outf,
    u16* __restrict__ outb, const float* __restrict__ res,
    int N, int K, int koff, int klen, bool addb)
{
    constexpr int MT = (BM == 128) ? 4 : 2;     // 16-row m-tiles per wave
    __shared__ u16 Als[2][BM * 32];
    __shared__ u16 Bls[2][128 * 32];
    const int tid = threadIdx.x;

    // ---- swizzled block mapping ----
    const int nbx = N >> 7;
    const int bid = blockIdx.x;
    const int G = nbx << 3;
    const int grp = bid / G;
    const int g = bid - grp * G;
    const int bm = (grp * 8 + (g & 7)) * BM;
    const int bn = (g >> 3) * 128;

    const int lane = tid & 63;
    const int w = tid >> 6;                      // wave 0..3
    const int wr = (BM == 128) ? (w >> 1) : (w & 1);
    const int wc = (BM == 128) ? (w & 1) : (w >> 1);
    const int lrow = lane & 15;
    const int lk = lane >> 4;

    f32x4 acc[MT][4] = {};

    auto stage = [&](int buf, int kk) {
        if (BM == 128) {
            #pragma unroll
            for (int s = 0; s < 2; ++s) {
                const int gb = w * 64 + s * 256;          // wave-uniform granule base
                const int j = gb >> 7, m0 = gb & 127;
                gll16(A + (size_t)(bm + m0 + lane) * K + kk + j * 8, Als[buf] + gb * 8);
            }
        } else {
            gll16(A + (size_t)(bm + lane) * K + kk + w * 8, Als[buf] + w * 64 * 8);
        }
        #pragma unroll
        for (int s = 0; s < 2; ++s) {
            const int gb = w * 64 + s * 256;
            const int j = gb >> 7, m0 = gb & 127;
            gll16(Bt + (size_t)(bn + m0 + lane) * K + kk + j * 8, Bls[buf] + gb * 8);
        }
    };

    const int niter = klen >> 5;
    stage(0, koff);
    for (int i = 0; i < niter; ++i) {
        __syncthreads();                          // loads into buf[i&1] landed
        if (i + 1 < niter) stage((i + 1) & 1, koff + (i + 1) * 32);
        const bf16x8* Af = (const bf16x8*)Als[i & 1];
        const bf16x8* Bf = (const bf16x8*)Bls[i & 1];
        bf16x8 af[MT], bfr[4];
        #pragma unroll
        for (int tm = 0; tm < MT; ++tm)
            af[tm] = Af[lk * BM + wr * (MT * 16) + tm * 16 + lrow];
        #pragma unroll
        for (int tn = 0; tn < 4; ++tn)
            bfr[tn] = Bf[lk * 128 + wc * 64 + tn * 16 + lrow];
        #pragma unroll
        for (int tm = 0; tm < MT; ++tm)
            #pragma unroll
            for (int tn = 0; tn < 4; ++tn)
                acc[tm][tn] = __builtin_amdgcn_mfma_f32_16x16x32_bf16(
                    af[tm], bfr[tn], acc[tm][tn], 0, 0, 0);
    }

    // ---- epilogue: D row = quad*4+reg, col = lane&15 (per 16x16 tile) ----
    int cg[4]; float bv[4];
    #pragma unroll
    for (int tn = 0; tn < 4; ++tn) {
        cg[tn] = bn + wc * 64 + tn * 16 + lrow;
        bv[tn] = addb ? bias[cg[tn]] : 0.0f;
    }
    #pragma unroll
    for (int tm = 0; tm < MT; ++tm) {
        const int rbase = bm + wr * (MT * 16) + tm * 16 + lk * 4;
        #pragma unroll
        for (int r = 0; r < 4; ++r) {
            const size_t rowoff = (size_t)(rbase + r) * N;
            #pragma unroll
            for (int tn = 0; tn < 4; ++tn) {
                float v = acc[tm][tn][r] + bv[tn];
                const size_t idx = rowoff + cg[tn];
                if (EPI == 0) outf[idx] = v;
                else if (EPI == 1) outf[idx] = v + res[idx];
                else if (EPI == 2) outb[idx] = f2bf(v);
                else if (EPI == 3) { outb[idx] = f2bf(gelu_fast(v)); }
                else { unsafeAtomicAdd(outf + idx, v); }   // EPI == 4, split-K
            }
        }
    }
}

template <int EPI, int BM>
__global__ __launch_bounds__(256) void mgemm(
    const u16* __restrict__ A, const u16* __restrict__ Bt,
    const float* __restrict__ bias, float* __restrict__ outf,
    u16* __restrict__ outb, const float* __restrict__ res,
    int N, int K)
{
    mgemm_core<EPI, BM>(A, Bt, bias, outf, outb, res, N, K, 0, K, true);
}

// split-K variant: grid.y = split index; partials atomically accumulated
// into outf (which must already hold the residual). Bias added by split 0.
template <int EPI, int BM>
__global__ __launch_bounds__(256) void mgemm_sk(
    const u16* __restrict__ A, const u16* __restrict__ Bt,
    const float* __restrict__ bias, float* __restrict__ outf,
    u16* __restrict__ outb, const float* __restrict__ res,
    int N, int K, int nsplit)
{
    const int split = blockIdx.y;
    const int klen = K / nsplit;
    mgemm_core<EPI, BM>(A, Bt, bias, outf, outb, res, N, K,
                        split * klen, klen, split == 0);
}

// fused embed GEMMs: z = 0(s) / 1(a) / 2(r)
__global__ __launch_bounds__(256) void mgemm_embed(
    const u16* __restrict__ U, const u16* __restrict__ Wt,
    const float* __restrict__ b0, const float* __restrict__ b1,
    const float* __restrict__ b2, float* __restrict__ out)
{
    const int z = blockIdx.z;
    const float* bias = (z == 0) ? b0 : (z == 1) ? b1 : b2;
    mgemm_core<0, 64>(U + (size_t)z * BT_ * KEP_, Wt + (size_t)z * H_ * KEP_,
                      bias, out + (size_t)z * BT_ * H_, nullptr, nullptr,
                      H_, KEP_, 0, KEP_, true);
}

// =====================================================================
// Vectorized weight transpose + fp32->bf16: W[K][N] -> Wt[N][Kpad].
// 32(K) x 64(N) tile, float4 loads, ushort4 stores. Zero-fill k >= K.
// Explicit (bx, by) tile coords so callers can pack multiple transposes
// into one flat-grid launch.
// =====================================================================
__device__ __forceinline__ void convT_core(
    const float* __restrict__ W, u16* __restrict__ Wt,
    int K, int N, int Kpad, int bx, int by)
{
    __shared__ float tile[32][65];
    const int k0 = by * 32, n0 = bx * 64;
    const int tid = threadIdx.x;
    #pragma unroll
    for (int p = 0; p < 2; ++p) {
        const int kr = (tid >> 4) + p * 16;
        const int nc = (tid & 15) * 4;
        const int k = k0 + kr;
        float4 v = make_float4(0.f, 0.f, 0.f, 0.f);
        if (k < K) v = *(const float4*)(W + (size_t)k * N + n0 + nc);
        tile[kr][nc + 0] = v.x; tile[kr][nc + 1] = v.y;
        tile[kr][nc + 2] = v.z; tile[kr][nc + 3] = v.w;
    }
    __syncthreads();
    #pragma unroll
    for (int p = 0; p < 2; ++p) {
        const int idx = tid + p * 256;
        const int n = idx >> 3, kq = (idx & 7) * 4;
        ushort4 o;
        o.x = f2bf(tile[kq + 0][n]); o.y = f2bf(tile[kq + 1][n]);
        o.z = f2bf(tile[kq + 2][n]); o.w = f2bf(tile[kq + 3][n]);
        *(ushort4*)(Wt + (size_t)(n0 + n) * Kpad + k0 + kq) = o;
    }
}

// one launch per layer: QKV+O (seg 0), W1 (seg 1), W2 (seg 2); 6144 blocks
__global__ __launch_bounds__(256) void convT_layer(
    const float* __restrict__ Wq, const float* __restrict__ Wk,
    const float* __restrict__ Wv, const float* __restrict__ Wo,
    const float* __restrict__ W1, const float* __restrict__ W2,
    const float* __restrict__ bq, const float* __restrict__ bk,
    const float* __restrict__ bv,
    u16* __restrict__ WQKVt, u16* __restrict__ Wot,
    u16* __restrict__ W1t, u16* __restrict__ W2t, float* __restrict__ bqkv)
{
    const int bid = blockIdx.x;
    const int seg = bid >> 11, r = bid & 2047;
    if (seg == 0) {
        const int z = r >> 9, rr = r & 511;          // 4 matrices x (16 x 32) tiles
        const int bx = rr & 15, by = rr >> 4;
        const float* W = (z == 0) ? Wq : (z == 1) ? Wk : (z == 2) ? Wv : Wo;
        u16* Wt = (z == 3) ? Wot : WQKVt + (size_t)z * H_ * H_;
        convT_core(W, Wt, H_, H_, H_, bx, by);
        if (bx == 0 && by == 0 && z < 3) {
            const float* bsrc = (z == 0) ? bq : (z == 1) ? bk : bv;
            #pragma unroll
            for (int u = 0; u < 4; ++u) {
                int i = threadIdx.x + u * 256;
                bqkv[z * H_ + i] = bsrc[i];
            }
        }
    } else if (seg == 1) {                           // W1: 64 x 32 tiles
        const int bx = r & 63, by = r >> 6;
        convT_core(W1, W1t, H_, NI_, H_, bx, by);
    } else {                                         // W2: 16 x 128 tiles
        const int bx = r & 15, by = r >> 4;
        convT_core(W2, W2t, NI_, H_, NI_, bx, by);
    }
}

// embed weights: z = 0(ts)/1(ta)/2(tr), each [KE_][H_] -> [H_][KEP_]
__global__ __launch_bounds__(256) void convT_embed(
    const float* __restrict__ W0, const float* __restrict__ W1,
    const float* __restrict__ W2, u16* __restrict__ Wt)
{
    const int z = blockIdx.z;
    const float* W = (z == 0) ? W0 : (z == 1) ? W1 : W2;
    convT_core(W, Wt + (size_t)z * H_ * KEP_, KE_, H_, KEP_, blockIdx.x, blockIdx.y);
}

// =====================================================================
// embedding pre-stage
// =====================================================================
__global__ __launch_bounds__(256) void embed_pre_kernel(
    const float* __restrict__ states, const float* __restrict__ actions,
    const float* __restrict__ rtgs, const float* __restrict__ mean,
    const float* __restrict__ stdv, const float* __restrict__ W_es,
    const float* __restrict__ b_es, const float* __restrict__ W_ea,
    const float* __restrict__ b_ea, const float* __restrict__ W_er,
    const float* __restrict__ b_er, const float* __restrict__ E_t,
    const int* __restrict__ timesteps,
    u16* __restrict__ Us, u16* __restrict__ Ua, u16* __restrict__ Ur)
{
    const int bt  = blockIdx.x;
    const int tid = threadIdx.x;
    __shared__ float sn[S_];
    __shared__ float tev[TIME_];
    if (tid < S_) sn[tid] = (states[bt * S_ + tid] - mean[tid]) / (stdv[tid] + 1e-9f);
    if (tid < TIME_) {
        int ts = timesteps[bt];
        tev[tid] = E_t[ts * TIME_ + tid];
    }
    __syncthreads();
    const float av = actions[bt];
    const float rv = rtgs[bt];
    const size_t rowo = (size_t)bt * KEP_;
    #pragma unroll
    for (int u = 0; u < 4; ++u) {
        int n = tid + u * 256;
        float accs = b_es[n];
        #pragma unroll
        for (int i = 0; i < S_; ++i) accs += sn[i] * W_es[i * H_ + n];
        Us[rowo + n] = f2bf(accs);
        Ua[rowo + n] = f2bf(av * W_ea[n] + b_ea[n]);
        Ur[rowo + n] = f2bf(rv * W_er[n] + b_er[n]);
    }
    if (tid < TIME_) {
        u16 tv = f2bf(tev[tid]);
        Us[rowo + H_ + tid] = tv;
        Ua[rowo + H_ + tid] = tv;
        Ur[rowo + H_ + tid] = tv;
    }
    if (tid < KEP_ - KE_) {
        Us[rowo + KE_ + tid] = 0;
        Ua[rowo + KE_ + tid] = 0;
        Ur[rowo + KE_ + tid] = 0;
    }
}

// =====================================================================
// LayerNorm over rows of 1024
// =====================================================================
template <bool BF16OUT>
__device__ __forceinline__ void ln_body(const float* __restrict__ src,
                                        const float* __restrict__ g,
                                        const float* __restrict__ b,
                                        void* __restrict__ dst,
                                        float* red, int tid)
{
    float v[4];
    #pragma unroll
    for (int u = 0; u < 4; ++u) v[u] = src[tid + u * 256];
    float s = v[0] + v[1] + v[2] + v[3];
    red[tid] = s; __syncthreads();
    for (int off = 128; off > 0; off >>= 1) {
        if (tid < off) red[tid] += red[tid + off];
        __syncthreads();
    }
    const float mean = red[0] * (1.0f / H_);
    __syncthreads();
    float ss = 0.0f;
    #pragma unroll
    for (int u = 0; u < 4; ++u) { float d = v[u] - mean; ss += d * d; }
    red[tid] = ss; __syncthreads();
    for (int off = 128; off > 0; off >>= 1) {
        if (tid < off) red[tid] += red[tid + off];
        __syncthreads();
    }
    const float var = red[0] * (1.0f / H_);
    const float rs = rsqrtf(var + 1e-5f);
    #pragma unroll
    for (int u = 0; u < 4; ++u) {
        int col = tid + u * 256;
        float y = (v[u] - mean) * rs * g[col] + b[col];
        if (BF16OUT) ((u16*)dst)[col] = f2bf(y);
        else ((float*)dst)[col] = y;
    }
}

__global__ __launch_bounds__(256) void ln_bf16_kernel(
    const float* __restrict__ X, const float* __restrict__ g,
    const float* __restrict__ b, u16* __restrict__ Y)
{
    __shared__ float red[256];
    const size_t row = blockIdx.x;
    ln_body<true>(X + row * H_, g, b, Y + row * H_, red, threadIdx.x);
}

__global__ __launch_bounds__(256) void interleave_eln_kernel(
    const float* __restrict__ RE, const float* __restrict__ SE,
    const float* __restrict__ AE, const float* __restrict__ g,
    const float* __restrict__ b, float* __restrict__ X)
{
    __shared__ float red[256];
    const int row = blockIdx.x;
    const int bi = row / T3_;
    const int rem = row % T3_;
    const int t = rem / 3, slot = rem % 3;
    const float* src = (slot == 0 ? RE : (slot == 1 ? SE : AE)) + (size_t)(bi * T_ + t) * H_;
    ln_body<false>(src, g, b, X + (size_t)row * H_, red, threadIdx.x);
}

// =====================================================================
// MFMA flash attention. Block = 64 Q-rows x (head, batch); wave = 16 rows.
// =====================================================================
__global__ __launch_bounds__(256) void attn_kernel(
    const u16* __restrict__ QKV, const float* __restrict__ amask,
    u16* __restrict__ Y)
{
    const int qt = blockIdx.x;   // 0..11
    const int h  = blockIdx.y;   // 0..15
    const int b  = blockIdx.z;   // 0..7
    const int tid = threadIdx.x;
    const int lane = tid & 63, w = tid >> 6;
    const int l15 = lane & 15, quad = lane >> 4;

    __shared__ u16 Kls[64][72];      // row-major K tile (+8 pad)
    __shared__ u16 Vt[64][72];       // transposed V tile: Vt[dh][token]
    __shared__ u16 Pls[4][16][72];   // per-wave P tile
    __shared__ float padv[64];

    const u16* Qbase = QKV + (size_t)b * T3_ * 3072 + h * 64;
    const u16* Kbase = Qbase + 1024;
    const u16* Vbase = Qbase + 2048;

    bf16x8 qf[2];
    {
        const u16* qp = Qbase + (size_t)(qt * 64 + w * 16 + l15) * 3072 + quad * 8;
        qf[0] = *(const bf16x8*)qp;
        qf[1] = *(const bf16x8*)(qp + 32);
    }

    float m_i[4], l_i[4];
    f32x4 o[4] = {};
    #pragma unroll
    for (int r = 0; r < 4; ++r) { m_i[r] = -3.0e30f; l_i[r] = 0.0f; }

    const int qr0 = qt * 64 + w * 16 + quad * 4;

    for (int kt = 0; kt <= qt; ++kt) {
        #pragma unroll
        for (int s = 0; s < 2; ++s) {
            const int c = tid + s * 256;
            const int tok = c >> 3, cb = c & 7;
            const size_t go = (size_t)(kt * 64 + tok) * 3072 + cb * 8;
            *(uint4*)&Kls[tok][cb * 8] = *(const uint4*)(Kbase + go);
            uint4 vv = *(const uint4*)(Vbase + go);
            const u16* vs = (const u16*)&vv;
            #pragma unroll
            for (int j = 0; j < 8; ++j) Vt[cb * 8 + j][tok] = vs[j];
        }
        if (tid < 64)
            padv[tid] = (1.0f - amask[b * T_ + (kt * 64 + tid) / 3]) * NEGV;
        __syncthreads();

        f32x4 sacc[4];
        #pragma unroll
        for (int nt = 0; nt < 4; ++nt) {
            bf16x8 kf0 = *(const bf16x8*)&Kls[nt * 16 + l15][quad * 8];
            bf16x8 kf1 = *(const bf16x8*)&Kls[nt * 16 + l15][32 + quad * 8];
            f32x4 z = {};
            z = __builtin_amdgcn_mfma_f32_16x16x32_bf16(qf[0], kf0, z, 0, 0, 0);
            sacc[nt] = __builtin_amdgcn_mfma_f32_16x16x32_bf16(qf[1], kf1, z, 0, 0, 0);
        }

        float sv[4][4];
        float rmax[4] = {-3.0e30f, -3.0e30f, -3.0e30f, -3.0e30f};
        #pragma unroll
        for (int nt = 0; nt < 4; ++nt) {
            const int jc = kt * 64 + nt * 16 + l15;
            const float pv = padv[nt * 16 + l15];
            #pragma unroll
            for (int r = 0; r < 4; ++r) {
                float v = (jc <= qr0 + r) ? sacc[nt][r] * 0.125f : NEGV;
                v += pv;
                sv[nt][r] = v;
                rmax[r] = fmaxf(rmax[r], v);
            }
        }
        #pragma unroll
        for (int m = 1; m < 16; m <<= 1)
            #pragma unroll
            for (int r = 0; r < 4; ++r)
                rmax[r] = fmaxf(rmax[r], __shfl_xor(rmax[r], m, 64));
        float al[4], rsum[4];
        #pragma unroll
        for (int r = 0; r < 4; ++r) {
            const float mn = fmaxf(m_i[r], rmax[r]);
            al[r] = __expf(m_i[r] - mn);
            m_i[r] = mn;
            float sum = 0.0f;
            #pragma unroll
            for (int nt = 0; nt < 4; ++nt) {
                float p = __expf(sv[nt][r] - mn);
                sv[nt][r] = p; sum += p;
            }
            rsum[r] = sum;
        }
        #pragma unroll
        for (int m = 1; m < 16; m <<= 1)
            #pragma unroll
            for (int r = 0; r < 4; ++r)
                rsum[r] += __shfl_xor(rsum[r], m, 64);
        #pragma unroll
        for (int r = 0; r < 4; ++r)
            l_i[r] = l_i[r] * al[r] + rsum[r];

        #pragma unroll
        for (int nt = 0; nt < 4; ++nt)
            #pragma unroll
            for (int r = 0; r < 4; ++r)
                Pls[w][quad * 4 + r][nt * 16 + l15] = f2bf(sv[nt][r]);
        #pragma unroll
        for (int dt = 0; dt < 4; ++dt)
            #pragma unroll
            for (int r = 0; r < 4; ++r)
                o[dt][r] *= al[r];

        bf16x8 pf0 = *(const bf16x8*)&Pls[w][l15][quad * 8];
        bf16x8 pf1 = *(const bf16x8*)&Pls[w][l15][32 + quad * 8];
        #pragma unroll
        for (int dt = 0; dt < 4; ++dt) {
            bf16x8 vf0 = *(const bf16x8*)&Vt[dt * 16 + l15][quad * 8];
            bf16x8 vf1 = *(const bf16x8*)&Vt[dt * 16 + l15][32 + quad * 8];
            o[dt] = __builtin_amdgcn_mfma_f32_16x16x32_bf16(pf0, vf0, o[dt], 0, 0, 0);
            o[dt] = __builtin_amdgcn_mfma_f32_16x16x32_bf16(pf1, vf1, o[dt], 0, 0, 0);
        }
        __syncthreads();
    }

    #pragma unroll
    for (int r = 0; r < 4; ++r) {
        const float inv = 1.0f / l_i[r];
        const size_t row = (size_t)b * T3_ + qt * 64 + w * 16 + quad * 4 + r;
        #pragma unroll
        for (int dt = 0; dt < 4; ++dt)
            Y[row * H_ + h * 64 + dt * 16 + l15] = f2bf(o[dt][r] * inv);
    }
}

// =====================================================================
// action head
// =====================================================================
__global__ __launch_bounds__(256) void head_kernel(
    const float* __restrict__ X, const float* __restrict__ W_pa,
    const float* __restrict__ b_pa, float* __restrict__ out)
{
    __shared__ float red[256];
    const int row = blockIdx.x;
    const int b = row / T_, t = row % T_;
    const float* x = X + ((size_t)b * T3_ + 3 * t + 1) * H_;
    const int tid = threadIdx.x;
    float s = 0.0f;
    #pragma unroll
    for (int u = 0; u < 4; ++u) {
        int col = tid + u * 256;
        s += x[col] * W_pa[col];
    }
    red[tid] = s; __syncthreads();
    for (int off = 128; off > 0; off >>= 1) {
        if (tid < off) red[tid] += red[tid + off];
        __syncthreads();
    }
    if (tid == 0) out[row] = red[0] + b_pa[0];
}

// =====================================================================
extern "C" void kernel_launch(void* const* d_in, const int* in_sizes, int n_in,
                              void* d_out, int out_size, void* d_ws, size_t ws_size,
                              hipStream_t stream)
{
    const float* states  = (const float*)d_in[0];
    const float* actions = (const float*)d_in[1];
    const float* rtgs    = (const float*)d_in[2];
    const float* amask   = (const float*)d_in[3];
    const float* smean   = (const float*)d_in[4];
    const float* sstd    = (const float*)d_in[5];
    const float* W_es    = (const float*)d_in[6];
    const float* b_es    = (const float*)d_in[7];
    const float* W_ea    = (const float*)d_in[8];
    const float* b_ea    = (const float*)d_in[9];
    const float* W_er    = (const float*)d_in[10];
    const float* b_er    = (const float*)d_in[11];
    const float* E_t     = (const float*)d_in[12];
    const float* W_ts    = (const float*)d_in[13];
    const float* b_ts    = (const float*)d_in[14];
    const float* W_ta    = (const float*)d_in[15];
    const float* b_ta    = (const float*)d_in[16];
    const float* W_tr    = (const float*)d_in[17];
    const float* b_tr    = (const float*)d_in[18];
    const float* eln_g   = (const float*)d_in[19];
    const float* eln_b   = (const float*)d_in[20];
    const float* ln1_g   = (const float*)d_in[21];
    const float* ln1_b   = (const float*)d_in[22];
    const float* ln2_g   = (const float*)d_in[23];
    const float* ln2_b   = (const float*)d_in[24];
    const float* Wq      = (const float*)d_in[25];
    const float* bq      = (const float*)d_in[26];
    const float* Wk      = (const float*)d_in[27];
    const float* bk      = (const float*)d_in[28];
    const float* Wv      = (const float*)d_in[29];
    const float* bv      = (const float*)d_in[30];
    const float* Wo      = (const float*)d_in[31];
    const float* bo      = (const float*)d_in[32];
    const float* W1      = (const float*)d_in[33];
    const float* b1      = (const float*)d_in[34];
    const float* W2      = (const float*)d_in[35];
    const float* b2      = (const float*)d_in[36];
    const float* W_pa    = (const float*)d_in[37];
    const float* b_pa    = (const float*)d_in[38];
    const int*   tsteps  = (const int*)d_in[39];
    float* out = (float*)d_out;

    // ---- workspace layout (bytes) ----
    char* base = (char*)d_ws;
    float* X    = (float*)base;                        // 25,165,824
    u16*   Hb   = (u16*)(base + 25165824);             // 12,582,912
    u16*   QKVb = (u16*)(base + 37748736);             // 37,748,736
    u16*   MIDb = (u16*)(base + 75497472);             // 50,331,648
    u16*   Wbuf = (u16*)(base + 125829120);            // 25,165,824 (end 150,994,944)

    float* bqkv = (float*)MIDb;
    u16* U_s = MIDb;
    u16* U_a = MIDb + (size_t)BT_ * KEP_;
    u16* U_r = MIDb + (size_t)2 * BT_ * KEP_;
    float* SE = (float*)QKVb;                          // SE, AE, RE consecutive
    float* AE = SE + (size_t)BT_ * H_;
    float* RE = AE + (size_t)BT_ * H_;
    u16* Wemb = Wbuf;                                  // 3 x [H_][KEP_]

    u16* WQKVt = Wbuf;                                 // [3072][1024]
    u16* Wot   = Wbuf + (size_t)3072 * 1024;           // [1024][1024]
    u16* W1t   = Wbuf + (size_t)4096 * 1024;           // [4096][1024]
    u16* W2t   = Wbuf + (size_t)8192 * 1024;           // [1024][4096]

    // ---- embedding ----
    embed_pre_kernel<<<BT_, 256, 0, stream>>>(
        states, actions, rtgs, smean, sstd, W_es, b_es, W_ea, b_ea,
        W_er, b_er, E_t, tsteps, U_s, U_a, U_r);

    dim3 gCvE(H_ / 64, KEP_ / 32, 3);                  // 16 x 33 x 3
    convT_embed<<<gCvE, 256, 0, stream>>>(W_ts, W_ta, W_tr, Wemb);

    dim3 gEmb((H_ / 128) * (BT_ / 64), 1, 3);          // 256 x 1 x 3
    mgemm_embed<<<gEmb, 256, 0, stream>>>(U_s, Wemb, b_ts, b_ta, b_tr, SE);

    interleave_eln_kernel<<<ROWS_, 256, 0, stream>>>(RE, SE, AE, eln_g, eln_b, X);

    // ---- transformer layers ----
    const int gQKV = (3072 / 128) * (ROWS_ / 128);     // 1152
    const int gO   = (H_ / 128) * (ROWS_ / 128);       // 384
    const int gM1  = (NI_ / 128) * (ROWS_ / 128);      // 1536
    dim3 gF2sk((H_ / 128) * (ROWS_ / 128), 4);         // 384 x 4 splits = 1536
    dim3 gAttn(T3_ / 64, NH_, B_);                     // 12 x 16 x 8

    for (int l = 0; l < L_; ++l) {
        const size_t wOff = (size_t)l * H_ * H_;
        const size_t bOff = (size_t)l * H_;
        const size_t w1Off = (size_t)l * H_ * NI_;
        const size_t b1Off = (size_t)l * NI_;

        convT_layer<<<6144, 256, 0, stream>>>(
            Wq + wOff, Wk + wOff, Wv + wOff, Wo + wOff,
            W1 + w1Off, W2 + w1Off,
            bq + bOff, bk + bOff, bv + bOff,
            WQKVt, Wot, W1t, W2t, bqkv);

        ln_bf16_kernel<<<ROWS_, 256, 0, stream>>>(X, ln1_g + bOff, ln1_b + bOff, Hb);
        mgemm<2, 128><<<gQKV, 256, 0, stream>>>(Hb, WQKVt, bqkv, nullptr, QKVb, nullptr, 3072, H_);
        attn_kernel<<<gAttn, 256, 0, stream>>>(QKVb, amask, Hb);
        mgemm<1, 128><<<gO, 256, 0, stream>>>(Hb, Wot, bo + bOff, X, nullptr, X, H_, H_);
        ln_bf16_kernel<<<ROWS_, 256, 0, stream>>>(X, ln2_g + bOff, ln2_b + bOff, Hb);
        mgemm<3, 128><<<gM1, 256, 0, stream>>>(Hb, W1t, b1 + b1Off, nullptr, MIDb, nullptr, NI_, H_);
        // FFN2: split-K=4, atomic accumulate into X (X holds residual)
        mgemm_sk<4, 128><<<gF2sk, 256, 0, stream>>>(MIDb, W2t, b2 + bOff, X, nullptr, nullptr, H_, NI_, 4);
    }

    head_kernel<<<BT_, 256, 0, stream>>>(X, W_pa, b_pa, out);
}

// Round 4
// 2808.696 us; speedup vs baseline: 1.1758x; 1.1657x over previous
//
#include <hip/hip_runtime.h>
#include <math.h>

// ---- problem dims ----
#define B_    8
#define T_    256
#define S_    16
#define H_    1024
#define NH_   16
#define L_    6
#define NI_   4096
#define TIME_ 8
#define T3_   768           // 3*T
#define DH_   64            // H/NH
#define BT_   2048          // B*T
#define ROWS_ 6144          // B*T3
#define KE_   1032          // H + TIME
#define KEP_  1056          // KE padded to multiple of 32
#define NEGV  (-10000.0f)

typedef unsigned short u16;
typedef short bf16x8 __attribute__((ext_vector_type(8)));   // 8 bf16 in 4 VGPRs
typedef float f32x4 __attribute__((ext_vector_type(4)));

__device__ __forceinline__ float bf2f(u16 u) {
    union { unsigned int i; float f; } x; x.i = ((unsigned int)u) << 16; return x.f;
}
__device__ __forceinline__ u16 f2bf(float f) {
    union { float f; unsigned int i; } x; x.f = f;
    unsigned int r = x.i + 0x7FFFu + ((x.i >> 16) & 1u);   // RNE
    return (u16)(r >> 16);
}
// tanh-form GELU via hw exp: |err vs exact erf-gelu| < ~6e-4 (threshold 6.8e-2)
__device__ __forceinline__ float gelu_fast(float x) {
    float y = 0.7978845608028654f * (x + 0.044715f * x * x * x);
    float e = __expf(2.0f * y);
    float t = 1.0f - 2.0f / (e + 1.0f);
    return 0.5f * x * (1.0f + t);
}

// async global->LDS 16B: lds dest is wave-uniform base + lane*16 (m97 pattern)
__device__ __forceinline__ void gll16(const u16* g, u16* l) {
    __builtin_amdgcn_global_load_lds(
        (const __attribute__((address_space(1))) unsigned int*)g,
        (__attribute__((address_space(3))) unsigned int*)l,
        16, 0, 0);
}

// =====================================================================
// 8-phase 256x256 bf16 GEMM (T2 swizzle + T3/T4 counted-vmcnt + T5 prio)
// C(M,N) = A(M,K) @ Bt(N,K)^T + bias.  BK=64, 512 threads = 8 waves
// (2M x 4N), per-wave 128x64 C.  LDS 128 KiB dynamic, double-buffered.
// Per K-tile: 4 phases x 16 MFMA; one half-tile staged per phase;
// vmcnt(4) once per K-tile (never 0 in steady state).
// LDS layout: row-major [row][64] u16, byte ^= ((row&7)<<4) swizzle,
// realized via inverse-swizzled GLOBAL source + swizzled ds_read addr
// (global_load_lds dest must stay linear).
// EPI: 1 = bias + residual(f32) -> f32, 2 = bias -> bf16,
//      3 = bias + gelu -> bf16
// Requires M%2048==0 (row-panel XCD grouping), N%256==0, K%64==0.
// =====================================================================
template <int EPI>
__global__ __launch_bounds__(512) void mgemm256(
    const u16* __restrict__ A, const u16* __restrict__ Bt,
    const float* __restrict__ bias, float* __restrict__ outf,
    u16* __restrict__ outb, const float* __restrict__ res,
    int N, int K)
{
    extern __shared__ u16 smem[];          // [buf][A 16384 | B 16384] u16
    const int tid  = threadIdx.x;
    const int lane = tid & 63, w = tid >> 6;
    const int l15  = lane & 15, quad = lane >> 4;
    const int wm   = w >> 2, wn = w & 3;   // wave grid 2(M) x 4(N)

    // ---- XCD-swizzled block mapping (8 row-panels per group) ----
    const int nbx = N >> 8;
    const int bid = blockIdx.x;
    const int G   = nbx << 3;
    const int grp = bid / G;
    const int g   = bid - grp * G;
    const int bm  = (grp * 8 + (g & 7)) * 256;
    const int bn  = (g >> 3) * 256;

    const int NT = K >> 6;                 // 64-wide K-tiles

    // stage half-tile ht of K-tile t: ht 0/1 = A half0/1, 2/3 = B half0/1.
    // linear LDS dest; global source inverse-swizzled so that the
    // swizzled read below sees the right element.
    auto stageHT = [&](int t, int ht) {
        u16* lbase = smem + (t & 1) * 32768 + ((ht & 2) ? 16384 : 0);
        const u16* gsrc = (ht & 2) ? Bt : A;
        const int rb = (ht & 2) ? bn : bm;
        const int k0 = t << 6;
        const int h  = ht & 1;
        #pragma unroll
        for (int s = 0; s < 2; ++s) {
            const int gb = h * 8192 + s * 4096 + w * 512;     // u16, wave-uniform
            const int p  = (gb + lane * 8) * 2;               // byte within tile
            const int lin = p ^ (((p >> 7) & 7) << 4);        // involution
            const int row = lin >> 7;
            const int cu  = (lin & 127) >> 1;
            gll16(gsrc + (size_t)(rb + row) * K + k0 + cu, lbase + gb);
        }
    };

    f32x4 acc[8][4] = {};

    // ---- prologue: tile0 fully + tile1 A halves; leave A(1) in flight ----
    stageHT(0, 0); stageHT(0, 1); stageHT(0, 2); stageHT(0, 3);
    stageHT(1, 0); stageHT(1, 1);
    asm volatile("s_waitcnt vmcnt(4)" ::: "memory");
    __builtin_amdgcn_s_barrier();

    const int swz = (l15 & 7) << 4;        // row&7 == l15&7 for all frags

    for (int t = 0; t < NT; ++t) {
        const u16* Ab = smem + (t & 1) * 32768;
        const u16* Bb = Ab + 16384;
        bf16x8 a0[4][2], a1[4][2], b0[2][2], b1[2][2];

        // ---- phase 1: read A-mh0 (8) + B-nh0 (4); stage B-h0(t+1); Q(0,0)
        #pragma unroll
        for (int f = 0; f < 4; ++f)
            #pragma unroll
            for (int ks = 0; ks < 2; ++ks)
                a0[f][ks] = *(const bf16x8*)((const char*)Ab +
                    (wm * 128 + f * 16 + l15) * 128 + ((ks * 64 + quad * 16) ^ swz));
        #pragma unroll
        for (int n = 0; n < 2; ++n)
            #pragma unroll
            for (int ks = 0; ks < 2; ++ks)
                b0[n][ks] = *(const bf16x8*)((const char*)Bb +
                    (wn * 64 + n * 16 + l15) * 128 + ((ks * 64 + quad * 16) ^ swz));
        if (t + 1 < NT) stageHT(t + 1, 2);
        __builtin_amdgcn_s_barrier();
        __builtin_amdgcn_s_setprio(1);
        #pragma unroll
        for (int f = 0; f < 4; ++f)
            #pragma unroll
            for (int n = 0; n < 2; ++n)
                #pragma unroll
                for (int ks = 0; ks < 2; ++ks)
                    acc[f][n] = __builtin_amdgcn_mfma_f32_16x16x32_bf16(
                        a0[f][ks], b0[n][ks], acc[f][n], 0, 0, 0);
        __builtin_amdgcn_s_setprio(0);
        __builtin_amdgcn_s_barrier();

        // ---- phase 2: read A-mh1 (8); stage B-h1(t+1); Q(1,0)
        #pragma unroll
        for (int f = 0; f < 4; ++f)
            #pragma unroll
            for (int ks = 0; ks < 2; ++ks)
                a1[f][ks] = *(const bf16x8*)((const char*)Ab +
                    (64 + wm * 128 + f * 16 + l15) * 128 + ((ks * 64 + quad * 16) ^ swz));
        if (t + 1 < NT) stageHT(t + 1, 3);
        __builtin_amdgcn_s_barrier();
        __builtin_amdgcn_s_setprio(1);
        #pragma unroll
        for (int f = 0; f < 4; ++f)
            #pragma unroll
            for (int n = 0; n < 2; ++n)
                #pragma unroll
                for (int ks = 0; ks < 2; ++ks)
                    acc[4 + f][n] = __builtin_amdgcn_mfma_f32_16x16x32_bf16(
                        a1[f][ks], b0[n][ks], acc[4 + f][n], 0, 0, 0);
        __builtin_amdgcn_s_setprio(0);
        __builtin_amdgcn_s_barrier();
        // all reads of this buffer's A region are complete past this barrier

        // ---- phase 3: read B-nh1 (4); stage A-h0(t+2) into THIS buf; Q(0,1)
        #pragma unroll
        for (int n = 0; n < 2; ++n)
            #pragma unroll
            for (int ks = 0; ks < 2; ++ks)
                b1[n][ks] = *(const bf16x8*)((const char*)Bb +
                    (32 + wn * 64 + n * 16 + l15) * 128 + ((ks * 64 + quad * 16) ^ swz));
        if (t + 2 < NT) stageHT(t + 2, 0);
        __builtin_amdgcn_s_barrier();
        __builtin_amdgcn_s_setprio(1);
        #pragma unroll
        for (int f = 0; f < 4; ++f)
            #pragma unroll
            for (int n = 0; n < 2; ++n)
                #pragma unroll
                for (int ks = 0; ks < 2; ++ks)
                    acc[f][2 + n] = __builtin_amdgcn_mfma_f32_16x16x32_bf16(
                        a0[f][ks], b1[n][ks], acc[f][2 + n], 0, 0, 0);
        __builtin_amdgcn_s_setprio(0);
        __builtin_amdgcn_s_barrier();

        // ---- phase 4: stage A-h1(t+2); counted vmcnt; Q(1,1)
        if (t + 2 < NT) {
            stageHT(t + 2, 1);
            asm volatile("s_waitcnt vmcnt(4)" ::: "memory");   // tile t+1 landed
        } else {
            asm volatile("s_waitcnt vmcnt(0)" ::: "memory");   // epilogue drain
        }
        __builtin_amdgcn_s_barrier();
        __builtin_amdgcn_s_setprio(1);
        #pragma unroll
        for (int f = 0; f < 4; ++f)
            #pragma unroll
            for (int n = 0; n < 2; ++n)
                #pragma unroll
                for (int ks = 0; ks < 2; ++ks)
                    acc[4 + f][2 + n] = __builtin_amdgcn_mfma_f32_16x16x32_bf16(
                        a1[f][ks], b1[n][ks], acc[4 + f][2 + n], 0, 0, 0);
        __builtin_amdgcn_s_setprio(0);
        __builtin_amdgcn_s_barrier();
    }

    // ---- epilogue: D row = quad*4+reg, col = lane&15 per 16x16 tile ----
    int cg[4]; float bv[4];
    #pragma unroll
    for (int n = 0; n < 4; ++n) {
        cg[n] = bn + wn * 64 + n * 16 + l15;
        bv[n] = bias[cg[n]];
    }
    #pragma unroll
    for (int mf = 0; mf < 8; ++mf) {
        const int rbase = bm + wm * 128 + mf * 16 + quad * 4;
        #pragma unroll
        for (int r = 0; r < 4; ++r) {
            const size_t rowoff = (size_t)(rbase + r) * N;
            #pragma unroll
            for (int n = 0; n < 4; ++n) {
                float v = acc[mf][n][r] + bv[n];
                const size_t idx = rowoff + cg[n];
                if (EPI == 1) outf[idx] = v + res[idx];
                else if (EPI == 2) outb[idx] = f2bf(v);
                else outb[idx] = f2bf(gelu_fast(v));
            }
        }
    }
}

// =====================================================================
// legacy bf16 MFMA GEMM core (m97 structure) — used for embed GEMM only
// =====================================================================
template <int EPI, int BM>
__device__ __forceinline__ void mgemm_core(
    const u16* __restrict__ A, const u16* __restrict__ Bt,
    const float* __restrict__ bias, float* __restrict__ outf,
    u16* __restrict__ outb, const float* __restrict__ res,
    int N, int K)
{
    constexpr int MT = (BM == 128) ? 4 : 2;
    __shared__ u16 Als[2][BM * 32];
    __shared__ u16 Bls[2][128 * 32];
    const int tid = threadIdx.x;

    const int nbx = N >> 7;
    const int bid = blockIdx.x;
    const int G = nbx << 3;
    const int grp = bid / G;
    const int g = bid - grp * G;
    const int bm = (grp * 8 + (g & 7)) * BM;
    const int bn = (g >> 3) * 128;

    const int lane = tid & 63;
    const int w = tid >> 6;
    const int wr = (BM == 128) ? (w >> 1) : (w & 1);
    const int wc = (BM == 128) ? (w & 1) : (w >> 1);
    const int lrow = lane & 15;
    const int lk = lane >> 4;

    f32x4 acc[MT][4] = {};

    auto stage = [&](int buf, int kk) {
        if (BM == 128) {
            #pragma unroll
            for (int s = 0; s < 2; ++s) {
                const int gb = w * 64 + s * 256;
                const int j = gb >> 7, m0 = gb & 127;
                gll16(A + (size_t)(bm + m0 + lane) * K + kk + j * 8, Als[buf] + gb * 8);
            }
        } else {
            gll16(A + (size_t)(bm + lane) * K + kk + w * 8, Als[buf] + w * 64 * 8);
        }
        #pragma unroll
        for (int s = 0; s < 2; ++s) {
            const int gb = w * 64 + s * 256;
            const int j = gb >> 7, m0 = gb & 127;
            gll16(Bt + (size_t)(bn + m0 + lane) * K + kk + j * 8, Bls[buf] + gb * 8);
        }
    };

    const int niter = K >> 5;
    stage(0, 0);
    for (int i = 0; i < niter; ++i) {
        __syncthreads();
        if (i + 1 < niter) stage((i + 1) & 1, (i + 1) * 32);
        const bf16x8* Af = (const bf16x8*)Als[i & 1];
        const bf16x8* Bf = (const bf16x8*)Bls[i & 1];
        bf16x8 af[MT], bfr[4];
        #pragma unroll
        for (int tm = 0; tm < MT; ++tm)
            af[tm] = Af[lk * BM + wr * (MT * 16) + tm * 16 + lrow];
        #pragma unroll
        for (int tn = 0; tn < 4; ++tn)
            bfr[tn] = Bf[lk * 128 + wc * 64 + tn * 16 + lrow];
        #pragma unroll
        for (int tm = 0; tm < MT; ++tm)
            #pragma unroll
            for (int tn = 0; tn < 4; ++tn)
                acc[tm][tn] = __builtin_amdgcn_mfma_f32_16x16x32_bf16(
                    af[tm], bfr[tn], acc[tm][tn], 0, 0, 0);
    }

    int cg[4]; float bv[4];
    #pragma unroll
    for (int tn = 0; tn < 4; ++tn) {
        cg[tn] = bn + wc * 64 + tn * 16 + lrow;
        bv[tn] = bias[cg[tn]];
    }
    #pragma unroll
    for (int tm = 0; tm < MT; ++tm) {
        const int rbase = bm + wr * (MT * 16) + tm * 16 + lk * 4;
        #pragma unroll
        for (int r = 0; r < 4; ++r) {
            const size_t rowoff = (size_t)(rbase + r) * N;
            #pragma unroll
            for (int tn = 0; tn < 4; ++tn) {
                float v = acc[tm][tn][r] + bv[tn];
                const size_t idx = rowoff + cg[tn];
                if (EPI == 0) outf[idx] = v;
                else if (EPI == 1) outf[idx] = v + res[idx];
                else if (EPI == 2) outb[idx] = f2bf(v);
                else { outb[idx] = f2bf(gelu_fast(v)); }
            }
        }
    }
}

// fused embed GEMMs: z = 0(s) / 1(a) / 2(r)
__global__ __launch_bounds__(256) void mgemm_embed(
    const u16* __restrict__ U, const u16* __restrict__ Wt,
    const float* __restrict__ b0, const float* __restrict__ b1,
    const float* __restrict__ b2, float* __restrict__ out)
{
    const int z = blockIdx.z;
    const float* bias = (z == 0) ? b0 : (z == 1) ? b1 : b2;
    mgemm_core<0, 64>(U + (size_t)z * BT_ * KEP_, Wt + (size_t)z * H_ * KEP_,
                      bias, out + (size_t)z * BT_ * H_, nullptr, nullptr,
                      H_, KEP_);
}

// =====================================================================
// Vectorized weight transpose + fp32->bf16: W[K][N] -> Wt[N][Kpad].
// =====================================================================
__device__ __forceinline__ void convT_core(
    const float* __restrict__ W, u16* __restrict__ Wt,
    int K, int N, int Kpad, int bx, int by)
{
    __shared__ float tile[32][65];
    const int k0 = by * 32, n0 = bx * 64;
    const int tid = threadIdx.x;
    #pragma unroll
    for (int p = 0; p < 2; ++p) {
        const int kr = (tid >> 4) + p * 16;
        const int nc = (tid & 15) * 4;
        const int k = k0 + kr;
        float4 v = make_float4(0.f, 0.f, 0.f, 0.f);
        if (k < K) v = *(const float4*)(W + (size_t)k * N + n0 + nc);
        tile[kr][nc + 0] = v.x; tile[kr][nc + 1] = v.y;
        tile[kr][nc + 2] = v.z; tile[kr][nc + 3] = v.w;
    }
    __syncthreads();
    #pragma unroll
    for (int p = 0; p < 2; ++p) {
        const int idx = tid + p * 256;
        const int n = idx >> 3, kq = (idx & 7) * 4;
        ushort4 o;
        o.x = f2bf(tile[kq + 0][n]); o.y = f2bf(tile[kq + 1][n]);
        o.z = f2bf(tile[kq + 2][n]); o.w = f2bf(tile[kq + 3][n]);
        *(ushort4*)(Wt + (size_t)(n0 + n) * Kpad + k0 + kq) = o;
    }
}

// one launch per layer: QKV+O (seg 0), W1 (seg 1), W2 (seg 2); 6144 blocks
__global__ __launch_bounds__(256) void convT_layer(
    const float* __restrict__ Wq, const float* __restrict__ Wk,
    const float* __restrict__ Wv, const float* __restrict__ Wo,
    const float* __restrict__ W1, const float* __restrict__ W2,
    const float* __restrict__ bq, const float* __restrict__ bk,
    const float* __restrict__ bv,
    u16* __restrict__ WQKVt, u16* __restrict__ Wot,
    u16* __restrict__ W1t, u16* __restrict__ W2t, float* __restrict__ bqkv)
{
    const int bid = blockIdx.x;
    const int seg = bid >> 11, r = bid & 2047;
    if (seg == 0) {
        const int z = r >> 9, rr = r & 511;
        const int bx = rr & 15, by = rr >> 4;
        const float* W = (z == 0) ? Wq : (z == 1) ? Wk : (z == 2) ? Wv : Wo;
        u16* Wt = (z == 3) ? Wot : WQKVt + (size_t)z * H_ * H_;
        convT_core(W, Wt, H_, H_, H_, bx, by);
        if (bx == 0 && by == 0 && z < 3) {
            const float* bsrc = (z == 0) ? bq : (z == 1) ? bk : bv;
            #pragma unroll
            for (int u = 0; u < 4; ++u) {
                int i = threadIdx.x + u * 256;
                bqkv[z * H_ + i] = bsrc[i];
            }
        }
    } else if (seg == 1) {
        const int bx = r & 63, by = r >> 6;
        convT_core(W1, W1t, H_, NI_, H_, bx, by);
    } else {
        const int bx = r & 15, by = r >> 4;
        convT_core(W2, W2t, NI_, H_, NI_, bx, by);
    }
}

// embed weights: z = 0(ts)/1(ta)/2(tr), each [KE_][H_] -> [H_][KEP_]
__global__ __launch_bounds__(256) void convT_embed(
    const float* __restrict__ W0, const float* __restrict__ W1,
    const float* __restrict__ W2, u16* __restrict__ Wt)
{
    const int z = blockIdx.z;
    const float* W = (z == 0) ? W0 : (z == 1) ? W1 : W2;
    convT_core(W, Wt + (size_t)z * H_ * KEP_, KE_, H_, KEP_, blockIdx.x, blockIdx.y);
}

// =====================================================================
// embedding pre-stage
// =====================================================================
__global__ __launch_bounds__(256) void embed_pre_kernel(
    const float* __restrict__ states, const float* __restrict__ actions,
    const float* __restrict__ rtgs, const float* __restrict__ mean,
    const float* __restrict__ stdv, const float* __restrict__ W_es,
    const float* __restrict__ b_es, const float* __restrict__ W_ea,
    const float* __restrict__ b_ea, const float* __restrict__ W_er,
    const float* __restrict__ b_er, const float* __restrict__ E_t,
    const int* __restrict__ timesteps,
    u16* __restrict__ Us, u16* __restrict__ Ua, u16* __restrict__ Ur)
{
    const int bt  = blockIdx.x;
    const int tid = threadIdx.x;
    __shared__ float sn[S_];
    __shared__ float tev[TIME_];
    if (tid < S_) sn[tid] = (states[bt * S_ + tid] - mean[tid]) / (stdv[tid] + 1e-9f);
    if (tid < TIME_) {
        int ts = timesteps[bt];
        tev[tid] = E_t[ts * TIME_ + tid];
    }
    __syncthreads();
    const float av = actions[bt];
    const float rv = rtgs[bt];
    const size_t rowo = (size_t)bt * KEP_;
    #pragma unroll
    for (int u = 0; u < 4; ++u) {
        int n = tid + u * 256;
        float accs = b_es[n];
        #pragma unroll
        for (int i = 0; i < S_; ++i) accs += sn[i] * W_es[i * H_ + n];
        Us[rowo + n] = f2bf(accs);
        Ua[rowo + n] = f2bf(av * W_ea[n] + b_ea[n]);
        Ur[rowo + n] = f2bf(rv * W_er[n] + b_er[n]);
    }
    if (tid < TIME_) {
        u16 tv = f2bf(tev[tid]);
        Us[rowo + H_ + tid] = tv;
        Ua[rowo + H_ + tid] = tv;
        Ur[rowo + H_ + tid] = tv;
    }
    if (tid < KEP_ - KE_) {
        Us[rowo + KE_ + tid] = 0;
        Ua[rowo + KE_ + tid] = 0;
        Ur[rowo + KE_ + tid] = 0;
    }
}

// =====================================================================
// LayerNorm over rows of 1024
// =====================================================================
template <bool BF16OUT>
__device__ __forceinline__ void ln_body(const float* __restrict__ src,
                                        const float* __restrict__ g,
                                        const float* __restrict__ b,
                                        void* __restrict__ dst,
                                        float* red, int tid)
{
    float v[4];
    #pragma unroll
    for (int u = 0; u < 4; ++u) v[u] = src[tid + u * 256];
    float s = v[0] + v[1] + v[2] + v[3];
    red[tid] = s; __syncthreads();
    for (int off = 128; off > 0; off >>= 1) {
        if (tid < off) red[tid] += red[tid + off];
        __syncthreads();
    }
    const float mean = red[0] * (1.0f / H_);
    __syncthreads();
    float ss = 0.0f;
    #pragma unroll
    for (int u = 0; u < 4; ++u) { float d = v[u] - mean; ss += d * d; }
    red[tid] = ss; __syncthreads();
    for (int off = 128; off > 0; off >>= 1) {
        if (tid < off) red[tid] += red[tid + off];
        __syncthreads();
    }
    const float var = red[0] * (1.0f / H_);
    const float rs = rsqrtf(var + 1e-5f);
    #pragma unroll
    for (int u = 0; u < 4; ++u) {
        int col = tid + u * 256;
        float y = (v[u] - mean) * rs * g[col] + b[col];
        if (BF16OUT) ((u16*)dst)[col] = f2bf(y);
        else ((float*)dst)[col] = y;
    }
}

__global__ __launch_bounds__(256) void ln_bf16_kernel(
    const float* __restrict__ X, const float* __restrict__ g,
    const float* __restrict__ b, u16* __restrict__ Y)
{
    __shared__ float red[256];
    const size_t row = blockIdx.x;
    ln_body<true>(X + row * H_, g, b, Y + row * H_, red, threadIdx.x);
}

__global__ __launch_bounds__(256) void interleave_eln_kernel(
    const float* __restrict__ RE, const float* __restrict__ SE,
    const float* __restrict__ AE, const float* __restrict__ g,
    const float* __restrict__ b, float* __restrict__ X)
{
    __shared__ float red[256];
    const int row = blockIdx.x;
    const int bi = row / T3_;
    const int rem = row % T3_;
    const int t = rem / 3, slot = rem % 3;
    const float* src = (slot == 0 ? RE : (slot == 1 ? SE : AE)) + (size_t)(bi * T_ + t) * H_;
    ln_body<false>(src, g, b, X + (size_t)row * H_, red, threadIdx.x);
}

// =====================================================================
// MFMA flash attention. Block = 64 Q-rows x (head, batch); wave = 16 rows.
// =====================================================================
__global__ __launch_bounds__(256) void attn_kernel(
    const u16* __restrict__ QKV, const float* __restrict__ amask,
    u16* __restrict__ Y)
{
    const int qt = blockIdx.x;   // 0..11
    const int h  = blockIdx.y;   // 0..15
    const int b  = blockIdx.z;   // 0..7
    const int tid = threadIdx.x;
    const int lane = tid & 63, w = tid >> 6;
    const int l15 = lane & 15, quad = lane >> 4;

    __shared__ u16 Kls[64][72];      // row-major K tile (+8 pad)
    __shared__ u16 Vt[64][72];       // transposed V tile: Vt[dh][token]
    __shared__ u16 Pls[4][16][72];   // per-wave P tile
    __shared__ float padv[64];

    const u16* Qbase = QKV + (size_t)b * T3_ * 3072 + h * 64;
    const u16* Kbase = Qbase + 1024;
    const u16* Vbase = Qbase + 2048;

    bf16x8 qf[2];
    {
        const u16* qp = Qbase + (size_t)(qt * 64 + w * 16 + l15) * 3072 + quad * 8;
        qf[0] = *(const bf16x8*)qp;
        qf[1] = *(const bf16x8*)(qp + 32);
    }

    float m_i[4], l_i[4];
    f32x4 o[4] = {};
    #pragma unroll
    for (int r = 0; r < 4; ++r) { m_i[r] = -3.0e30f; l_i[r] = 0.0f; }

    const int qr0 = qt * 64 + w * 16 + quad * 4;

    for (int kt = 0; kt <= qt; ++kt) {
        #pragma unroll
        for (int s = 0; s < 2; ++s) {
            const int c = tid + s * 256;
            const int tok = c >> 3, cb = c & 7;
            const size_t go = (size_t)(kt * 64 + tok) * 3072 + cb * 8;
            *(uint4*)&Kls[tok][cb * 8] = *(const uint4*)(Kbase + go);
            uint4 vv = *(const uint4*)(Vbase + go);
            const u16* vs = (const u16*)&vv;
            #pragma unroll
            for (int j = 0; j < 8; ++j) Vt[cb * 8 + j][tok] = vs[j];
        }
        if (tid < 64)
            padv[tid] = (1.0f - amask[b * T_ + (kt * 64 + tid) / 3]) * NEGV;
        __syncthreads();

        f32x4 sacc[4];
        #pragma unroll
        for (int nt = 0; nt < 4; ++nt) {
            bf16x8 kf0 = *(const bf16x8*)&Kls[nt * 16 + l15][quad * 8];
            bf16x8 kf1 = *(const bf16x8*)&Kls[nt * 16 + l15][32 + quad * 8];
            f32x4 z = {};
            z = __builtin_amdgcn_mfma_f32_16x16x32_bf16(qf[0], kf0, z, 0, 0, 0);
            sacc[nt] = __builtin_amdgcn_mfma_f32_16x16x32_bf16(qf[1], kf1, z, 0, 0, 0);
        }

        float sv[4][4];
        float rmax[4] = {-3.0e30f, -3.0e30f, -3.0e30f, -3.0e30f};
        #pragma unroll
        for (int nt = 0; nt < 4; ++nt) {
            const int jc = kt * 64 + nt * 16 + l15;
            const float pv = padv[nt * 16 + l15];
            #pragma unroll
            for (int r = 0; r < 4; ++r) {
                float v = (jc <= qr0 + r) ? sacc[nt][r] * 0.125f : NEGV;
                v += pv;
                sv[nt][r] = v;
                rmax[r] = fmaxf(rmax[r], v);
            }
        }
        #pragma unroll
        for (int m = 1; m < 16; m <<= 1)
            #pragma unroll
            for (int r = 0; r < 4; ++r)
                rmax[r] = fmaxf(rmax[r], __shfl_xor(rmax[r], m, 64));
        float al[4], rsum[4];
        #pragma unroll
        for (int r = 0; r < 4; ++r) {
            const float mn = fmaxf(m_i[r], rmax[r]);
            al[r] = __expf(m_i[r] - mn);
            m_i[r] = mn;
            float sum = 0.0f;
            #pragma unroll
            for (int nt = 0; nt < 4; ++nt) {
                float p = __expf(sv[nt][r] - mn);
                sv[nt][r] = p; sum += p;
            }
            rsum[r] = sum;
        }
        #pragma unroll
        for (int m = 1; m < 16; m <<= 1)
            #pragma unroll
            for (int r = 0; r < 4; ++r)
                rsum[r] += __shfl_xor(rsum[r], m, 64);
        #pragma unroll
        for (int r = 0; r < 4; ++r)
            l_i[r] = l_i[r] * al[r] + rsum[r];

        #pragma unroll
        for (int nt = 0; nt < 4; ++nt)
            #pragma unroll
            for (int r = 0; r < 4; ++r)
                Pls[w][quad * 4 + r][nt * 16 + l15] = f2bf(sv[nt][r]);
        #pragma unroll
        for (int dt = 0; dt < 4; ++dt)
            #pragma unroll
            for (int r = 0; r < 4; ++r)
                o[dt][r] *= al[r];

        bf16x8 pf0 = *(const bf16x8*)&Pls[w][l15][quad * 8];
        bf16x8 pf1 = *(const bf16x8*)&Pls[w][l15][32 + quad * 8];
        #pragma unroll
        for (int dt = 0; dt < 4; ++dt) {
            bf16x8 vf0 = *(const bf16x8*)&Vt[dt * 16 + l15][quad * 8];
            bf16x8 vf1 = *(const bf16x8*)&Vt[dt * 16 + l15][32 + quad * 8];
            o[dt] = __builtin_amdgcn_mfma_f32_16x16x32_bf16(pf0, vf0, o[dt], 0, 0, 0);
            o[dt] = __builtin_amdgcn_mfma_f32_16x16x32_bf16(pf1, vf1, o[dt], 0, 0, 0);
        }
        __syncthreads();
    }

    #pragma unroll
    for (int r = 0; r < 4; ++r) {
        const float inv = 1.0f / l_i[r];
        const size_t row = (size_t)b * T3_ + qt * 64 + w * 16 + quad * 4 + r;
        #pragma unroll
        for (int dt = 0; dt < 4; ++dt)
            Y[row * H_ + h * 64 + dt * 16 + l15] = f2bf(o[dt][r] * inv);
    }
}

// =====================================================================
// action head
// =====================================================================
__global__ __launch_bounds__(256) void head_kernel(
    const float* __restrict__ X, const float* __restrict__ W_pa,
    const float* __restrict__ b_pa, float* __restrict__ out)
{
    __shared__ float red[256];
    const int row = blockIdx.x;
    const int b = row / T_, t = row % T_;
    const float* x = X + ((size_t)b * T3_ + 3 * t + 1) * H_;
    const int tid = threadIdx.x;
    float s = 0.0f;
    #pragma unroll
    for (int u = 0; u < 4; ++u) {
        int col = tid + u * 256;
        s += x[col] * W_pa[col];
    }
    red[tid] = s; __syncthreads();
    for (int off = 128; off > 0; off >>= 1) {
        if (tid < off) red[tid] += red[tid + off];
        __syncthreads();
    }
    if (tid == 0) out[row] = red[0] + b_pa[0];
}

// =====================================================================
extern "C" void kernel_launch(void* const* d_in, const int* in_sizes, int n_in,
                              void* d_out, int out_size, void* d_ws, size_t ws_size,
                              hipStream_t stream)
{
    const float* states  = (const float*)d_in[0];
    const float* actions = (const float*)d_in[1];
    const float* rtgs    = (const float*)d_in[2];
    const float* amask   = (const float*)d_in[3];
    const float* smean   = (const float*)d_in[4];
    const float* sstd    = (const float*)d_in[5];
    const float* W_es    = (const float*)d_in[6];
    const float* b_es    = (const float*)d_in[7];
    const float* W_ea    = (const float*)d_in[8];
    const float* b_ea    = (const float*)d_in[9];
    const float* W_er    = (const float*)d_in[10];
    const float* b_er    = (const float*)d_in[11];
    const float* E_t     = (const float*)d_in[12];
    const float* W_ts    = (const float*)d_in[13];
    const float* b_ts    = (const float*)d_in[14];
    const float* W_ta    = (const float*)d_in[15];
    const float* b_ta    = (const float*)d_in[16];
    const float* W_tr    = (const float*)d_in[17];
    const float* b_tr    = (const float*)d_in[18];
    const float* eln_g   = (const float*)d_in[19];
    const float* eln_b   = (const float*)d_in[20];
    const float* ln1_g   = (const float*)d_in[21];
    const float* ln1_b   = (const float*)d_in[22];
    const float* ln2_g   = (const float*)d_in[23];
    const float* ln2_b   = (const float*)d_in[24];
    const float* Wq      = (const float*)d_in[25];
    const float* bq      = (const float*)d_in[26];
    const float* Wk      = (const float*)d_in[27];
    const float* bk      = (const float*)d_in[28];
    const float* Wv      = (const float*)d_in[29];
    const float* bv      = (const float*)d_in[30];
    const float* Wo      = (const float*)d_in[31];
    const float* bo      = (const float*)d_in[32];
    const float* W1      = (const float*)d_in[33];
    const float* b1      = (const float*)d_in[34];
    const float* W2      = (const float*)d_in[35];
    const float* b2      = (const float*)d_in[36];
    const float* W_pa    = (const float*)d_in[37];
    const float* b_pa    = (const float*)d_in[38];
    const int*   tsteps  = (const int*)d_in[39];
    float* out = (float*)d_out;

    // raise dynamic LDS cap for the 8-phase kernels (once)
    static bool attrset = false;
    if (!attrset) {
        hipFuncSetAttribute(reinterpret_cast<const void*>(mgemm256<1>),
                            hipFuncAttributeMaxDynamicSharedMemorySize, 131072);
        hipFuncSetAttribute(reinterpret_cast<const void*>(mgemm256<2>),
                            hipFuncAttributeMaxDynamicSharedMemorySize, 131072);
        hipFuncSetAttribute(reinterpret_cast<const void*>(mgemm256<3>),
                            hipFuncAttributeMaxDynamicSharedMemorySize, 131072);
        attrset = true;
    }

    // ---- workspace layout (bytes) ----
    char* base = (char*)d_ws;
    float* X    = (float*)base;                        // 25,165,824
    u16*   Hb   = (u16*)(base + 25165824);             // 12,582,912
    u16*   QKVb = (u16*)(base + 37748736);             // 37,748,736
    u16*   MIDb = (u16*)(base + 75497472);             // 50,331,648
    u16*   Wbuf = (u16*)(base + 125829120);            // 25,165,824 (end 150,994,944)

    float* bqkv = (float*)MIDb;
    u16* U_s = MIDb;
    u16* U_a = MIDb + (size_t)BT_ * KEP_;
    u16* U_r = MIDb + (size_t)2 * BT_ * KEP_;
    float* SE = (float*)QKVb;                          // SE, AE, RE consecutive
    float* AE = SE + (size_t)BT_ * H_;
    float* RE = AE + (size_t)BT_ * H_;
    u16* Wemb = Wbuf;                                  // 3 x [H_][KEP_]

    u16* WQKVt = Wbuf;                                 // [3072][1024]
    u16* Wot   = Wbuf + (size_t)3072 * 1024;           // [1024][1024]
    u16* W1t   = Wbuf + (size_t)4096 * 1024;           // [4096][1024]
    u16* W2t   = Wbuf + (size_t)8192 * 1024;           // [1024][4096]

    // ---- embedding ----
    embed_pre_kernel<<<BT_, 256, 0, stream>>>(
        states, actions, rtgs, smean, sstd, W_es, b_es, W_ea, b_ea,
        W_er, b_er, E_t, tsteps, U_s, U_a, U_r);

    dim3 gCvE(H_ / 64, KEP_ / 32, 3);                  // 16 x 33 x 3
    convT_embed<<<gCvE, 256, 0, stream>>>(W_ts, W_ta, W_tr, Wemb);

    dim3 gEmb((H_ / 128) * (BT_ / 64), 1, 3);          // 256 x 1 x 3
    mgemm_embed<<<gEmb, 256, 0, stream>>>(U_s, Wemb, b_ts, b_ta, b_tr, SE);

    interleave_eln_kernel<<<ROWS_, 256, 0, stream>>>(RE, SE, AE, eln_g, eln_b, X);

    // ---- transformer layers (8-phase 256^2 GEMMs) ----
    const int gQKV = (3072 / 256) * (ROWS_ / 256);     // 288
    const int gO   = (H_ / 256) * (ROWS_ / 256);       // 96
    const int gM1  = (NI_ / 256) * (ROWS_ / 256);      // 384
    dim3 gAttn(T3_ / 64, NH_, B_);                     // 12 x 16 x 8

    for (int l = 0; l < L_; ++l) {
        const size_t wOff = (size_t)l * H_ * H_;
        const size_t bOff = (size_t)l * H_;
        const size_t w1Off = (size_t)l * H_ * NI_;
        const size_t b1Off = (size_t)l * NI_;

        convT_layer<<<6144, 256, 0, stream>>>(
            Wq + wOff, Wk + wOff, Wv + wOff, Wo + wOff,
            W1 + w1Off, W2 + w1Off,
            bq + bOff, bk + bOff, bv + bOff,
            WQKVt, Wot, W1t, W2t, bqkv);

        ln_bf16_kernel<<<ROWS_, 256, 0, stream>>>(X, ln1_g + bOff, ln1_b + bOff, Hb);
        mgemm256<2><<<gQKV, 512, 131072, stream>>>(Hb, WQKVt, bqkv, nullptr, QKVb, nullptr, 3072, H_);
        attn_kernel<<<gAttn, 256, 0, stream>>>(QKVb, amask, Hb);
        mgemm256<1><<<gO, 512, 131072, stream>>>(Hb, Wot, bo + bOff, X, nullptr, X, H_, H_);
        ln_bf16_kernel<<<ROWS_, 256, 0, stream>>>(X, ln2_g + bOff, ln2_b + bOff, Hb);
        mgemm256<3><<<gM1, 512, 131072, stream>>>(Hb, W1t, b1 + b1Off, nullptr, MIDb, nullptr, NI_, H_);
        mgemm256<1><<<gO, 512, 131072, stream>>>(MIDb, W2t, b2 + bOff, X, nullptr, X, H_, NI_);
    }

    head_kernel<<<BT_, 256, 0, stream>>>(X, W_pa, b_pa, out);
}